// Round 4
// baseline (448.663 us; speedup 1.0000x reference)
//
#include <hip/hip_runtime.h>
#include <hip/hip_bf16.h>
#include <cstdint>
#include <cstddef>

#define N 4096
#define NN ((size_t)N * (size_t)N)

typedef int int4v  __attribute__((ext_vector_type(4)));
typedef int int16v __attribute__((ext_vector_type(16)));

__device__ inline void async16(const void* g, void* lds) {
    __builtin_amdgcn_global_load_lds(
        (const __attribute__((address_space(1))) void*)g,
        (__attribute__((address_space(3))) void*)lds, 16, 0, 0);
}

// exact op-for-op match of the numpy reference (absmax 0.0 in rounds 1-3)
__device__ inline float mod_elem(float p, float uu, float o) {
    p = fminf(fmaxf(p, 1e-10f), 1.0f - 1e-10f);
    float logits = logf(p) - log1pf(-p);
    float noise  = logf(uu) - log1pf(-uu);
    float y = (logits + noise) / 0.2f;
    float soft = 1.0f / (1.0f + expf(-y));
    float hard = rintf(soft);
    return o + hard * (-2.0f * o);
}

// ---------------- kernel 1: diagonal mod prepass + zero accumulators ----------------
__global__ void diag_kernel(const float* __restrict__ ori, const float* __restrict__ clp,
                            const float* __restrict__ u, float* __restrict__ diag,
                            double* __restrict__ accs) {
    int j = blockIdx.x * blockDim.x + threadIdx.x;  // 4096 threads
    size_t idx = (size_t)j * N + j;
    diag[j] = mod_elem(clp[idx], u[idx], ori[idx]);
    if (blockIdx.x == 0 && threadIdx.x < 2) accs[threadIdx.x] = 0.0;
}

// ---------------- kernel 2: fused mod + A-build over symmetric 32x32 tile pairs ----------------
// Block (bx<=by) computes mod tiles (bi,bj) and (bj,bi) (each element once), writes mod to out,
// then A[i][j] = mod[i][j] + mod[j][i] - mod[j][j] as i8 into A, AT, |A|, |A|T for both tiles.
__global__ __launch_bounds__(256) void fused_mod_A(
        const float* __restrict__ ori, const float* __restrict__ clp,
        const float* __restrict__ u, const float* __restrict__ diag,
        float* __restrict__ out,
        signed char* __restrict__ A, signed char* __restrict__ AT,
        signed char* __restrict__ Aa, signed char* __restrict__ ATa) {
    const int bx = blockIdx.x, by = blockIdx.y;
    if (bx > by) return;
    const int bi = bx * 32, bj = by * 32;
    __shared__ float mij[32][33];   // mij[il][jl] = mod[bi+il][bj+jl]
    __shared__ float mji[32][33];   // mji[jl][il] = mod[bj+jl][bi+il]
    const int t = threadIdx.x;
    const int r  = t >> 3;          // 0..31
    const int c4 = (t & 7) * 4;     // 0,4,..,28
    {
        size_t idx = (size_t)(bi + r) * N + bj + c4;
        float4 p4 = *(const float4*)&clp[idx];
        float4 u4 = *(const float4*)&u[idx];
        float4 o4 = *(const float4*)&ori[idx];
        float m0 = mod_elem(p4.x, u4.x, o4.x);
        float m1 = mod_elem(p4.y, u4.y, o4.y);
        float m2 = mod_elem(p4.z, u4.z, o4.z);
        float m3 = mod_elem(p4.w, u4.w, o4.w);
        *(float4*)&out[idx] = make_float4(m0, m1, m2, m3);
        mij[r][c4] = m0; mij[r][c4 + 1] = m1; mij[r][c4 + 2] = m2; mij[r][c4 + 3] = m3;
        if (bx != by) {
            size_t idx2 = (size_t)(bj + r) * N + bi + c4;
            float4 q4 = *(const float4*)&clp[idx2];
            float4 v4 = *(const float4*)&u[idx2];
            float4 w4 = *(const float4*)&ori[idx2];
            float n0 = mod_elem(q4.x, v4.x, w4.x);
            float n1 = mod_elem(q4.y, v4.y, w4.y);
            float n2 = mod_elem(q4.z, v4.z, w4.z);
            float n3 = mod_elem(q4.w, v4.w, w4.w);
            *(float4*)&out[idx2] = make_float4(n0, n1, n2, n3);
            mji[r][c4] = n0; mji[r][c4 + 1] = n1; mji[r][c4 + 2] = n2; mji[r][c4 + 3] = n3;
        } else {
            mji[r][c4] = m0; mji[r][c4 + 1] = m1; mji[r][c4 + 2] = m2; mji[r][c4 + 3] = m3;
        }
    }
    __syncthreads();
    const float djr = diag[bj + r];
    const float dir = diag[bi + r];
    int pkA = 0, pkAa = 0, pkT = 0, pkTa = 0;
    int qkA = 0, qkAa = 0, qkT = 0, qkTa = 0;
    #pragma unroll
    for (int k = 0; k < 4; ++k) {
        const int c = c4 + k;
        const float x = mij[r][c], xt = mij[c][r];
        const float y = mji[r][c], yt = mji[c][r];
        // A tile (bi,bj): A[bi+r][bj+c] = mij + mjiT - diag[bj+c]
        int ai = (int)(x + yt - diag[bj + c]);
        // AT rows bj: AT[bj+r][bi+c] = A[bi+c][bj+r] = mij[c][r] + mji[r][c] - diag[bj+r]
        int ti = (int)(xt + y - djr);
        pkA  |= (ai & 255) << (8 * k);
        pkAa |= ((ai < 0 ? -ai : ai) & 255) << (8 * k);
        pkT  |= (ti & 255) << (8 * k);
        pkTa |= ((ti < 0 ? -ti : ti) & 255) << (8 * k);
        // mirror tile (bj,bi): A[bj+r][bi+c] = mji[r][c] + mij[c][r] - diag[bi+c]
        int mi = (int)(y + xt - diag[bi + c]);
        // AT rows bi: AT[bi+r][bj+c] = A[bj+c][bi+r] = mji[c][r] + mij[r][c] - diag[bi+r]
        int si = (int)(yt + x - dir);
        qkA  |= (mi & 255) << (8 * k);
        qkAa |= ((mi < 0 ? -mi : mi) & 255) << (8 * k);
        qkT  |= (si & 255) << (8 * k);
        qkTa |= ((si < 0 ? -si : si) & 255) << (8 * k);
    }
    const size_t o1 = (size_t)(bi + r) * N + bj + c4;   // tile (bi,bj) rows
    const size_t o2 = (size_t)(bj + r) * N + bi + c4;   // tile (bj,bi) rows
    *(int*)&A [o1] = pkA;  *(int*)&Aa [o1] = pkAa;
    *(int*)&AT[o2] = pkT;  *(int*)&ATa[o2] = pkTa;
    if (bx != by) {
        *(int*)&A [o2] = qkA;  *(int*)&Aa [o2] = qkAa;
        *(int*)&AT[o1] = qkT;  *(int*)&ATa[o1] = qkTa;
    }
}

// ---------------- kernel 3: i8 GEMM-trace, 32x32x32 MFMA, BK=128, XOR swizzle ----------------
// acc[z] = sum_{i,k} (M.M)[i,k] * M[k,i], M = A (z=0) or |A| (z=1). Exact integer math.
// LDS rows are 64 B (4 chunks of 16B), stored slot = chunk ^ ((row>>1)&3) — conflict-free
// for both the lane-16B staging and the frag reads (8 consecutive lanes sweep all 8 bank groups).
__global__ __launch_bounds__(256) void gemm_trace_i8(const signed char* __restrict__ Ag,
                                                     const signed char* __restrict__ ATg,
                                                     const signed char* __restrict__ Aag,
                                                     const signed char* __restrict__ ATag,
                                                     double* __restrict__ accs) {
    __shared__ int4v As4[1024];   // [0..511]=K 0..63, [512..1023]=K 64..127
    __shared__ int4v Bs4[1024];
    __shared__ int red[4];
    const int z = blockIdx.z;
    const signed char* Asrc = z ? Aag  : Ag;    // M rows   (i-panel)
    const signed char* Bsrc = z ? ATag : ATg;   // MT rows  (k-panel), B[k][n] = MT[n][k]
    const int i0 = blockIdx.y * 128;
    const int k0 = blockIdx.x * 128;
    const int t = threadIdx.x;
    const int lane = t & 63;
    const int wave = t >> 6;
    const int wr = (wave >> 1) * 64;
    const int wc = (wave & 1) * 64;
    const int m32 = lane & 31;
    const int kg  = lane >> 5;     // k-group within frag
    signed char* Asc = (signed char*)As4;
    signed char* Bsc = (signed char*)Bs4;

    const int r0 = t >> 2;               // 0..63
    const int c0 = (t & 3) ^ ((r0 >> 1) & 3);
    const signed char* gA = Asrc + (size_t)(i0 + r0) * N + c0 * 16;
    const signed char* gB = Bsrc + (size_t)(k0 + r0) * N + c0 * 16;
    const int ldst = t * 16;

    int16v acc[2][2];
    #pragma unroll
    for (int a = 0; a < 2; ++a)
        #pragma unroll
        for (int b = 0; b < 2; ++b)
            acc[a][b] = (int16v)(0);

    for (int kb = 0; kb < N; kb += 128) {
        __syncthreads();
        const signed char* ga = gA + kb;
        const signed char* gb = gB + kb;
        async16(ga,               Asc + ldst);            // K 0..63,  rows 0..63
        async16(ga + 64 * N,      Asc + 4096  + ldst);    // K 0..63,  rows 64..127
        async16(ga + 64,          Asc + 8192  + ldst);    // K 64..127, rows 0..63
        async16(ga + 64 * N + 64, Asc + 12288 + ldst);    // K 64..127, rows 64..127
        async16(gb,               Bsc + ldst);
        async16(gb + 64 * N,      Bsc + 4096  + ldst);
        async16(gb + 64,          Bsc + 8192  + ldst);
        async16(gb + 64 * N + 64, Bsc + 12288 + ldst);
        __syncthreads();
        #pragma unroll
        for (int half = 0; half < 2; ++half) {
            const int hb = half * 8192;
            #pragma unroll
            for (int q = 0; q < 2; ++q) {
                int4v af[2], bf[2];
                #pragma unroll
                for (int tr = 0; tr < 2; ++tr) {
                    const int row = wr + tr * 32 + m32;
                    const int slot = (q * 2 + kg) ^ ((row >> 1) & 3);
                    af[tr] = *(const int4v*)(Asc + hb + (row << 6) + (slot << 4));
                }
                #pragma unroll
                for (int tc = 0; tc < 2; ++tc) {
                    const int row = wc + tc * 32 + m32;
                    const int slot = (q * 2 + kg) ^ ((row >> 1) & 3);
                    bf[tc] = *(const int4v*)(Bsc + hb + (row << 6) + (slot << 4));
                }
                #pragma unroll
                for (int tr = 0; tr < 2; ++tr)
                    #pragma unroll
                    for (int tc = 0; tc < 2; ++tc)
                        acc[tr][tc] = __builtin_amdgcn_mfma_i32_32x32x32_i8(
                            af[tr], bf[tc], acc[tr][tc], 0, 0, 0);
            }
        }
    }

    // trace epilogue: 32x32 C/D layout col=lane&31, row=(reg&3)+8*(reg>>2)+4*(lane>>5)
    // (m74/m101-verified, dtype-independent). multiplier M[k,i] = MT[i,k] = Bsrc[i*N + k].
    int part = 0;
    const int rbase = 4 * kg;
    #pragma unroll
    for (int tr = 0; tr < 2; ++tr) {
        #pragma unroll
        for (int tc = 0; tc < 2; ++tc) {
            const int ib = i0 + wr + tr * 32;
            const int kk = k0 + wc + tc * 32 + m32;
            #pragma unroll
            for (int reg = 0; reg < 16; ++reg) {
                const int row = (reg & 3) + 8 * (reg >> 2) + rbase;
                part += acc[tr][tc][reg] * (int)Bsrc[(size_t)(ib + row) * N + kk];
            }
        }
    }
    #pragma unroll
    for (int off = 32; off > 0; off >>= 1)
        part += __shfl_down(part, off, 64);
    if (lane == 0) red[wave] = part;
    __syncthreads();
    if (t == 0) {
        int tot = red[0] + red[1] + red[2] + red[3];
        atomicAdd(&accs[z], (double)tot);
    }
}

// ---------------- kernel 4: balance ----------------
__global__ void finalize_kernel(const double* __restrict__ accs, float* __restrict__ out) {
    out[NN] = (float)(0.5 * (1.0 + accs[0] / accs[1]));
}

extern "C" void kernel_launch(void* const* d_in, const int* in_sizes, int n_in,
                              void* d_out, int out_size, void* d_ws, size_t ws_size,
                              hipStream_t stream) {
    const float* ori = (const float*)d_in[0];
    const float* clp = (const float*)d_in[1];
    const float* u   = (const float*)d_in[2];
    float* out = (float*)d_out;
    char* ws = (char*)d_ws;
    signed char* A8   = (signed char*)ws;                    // 16 MiB
    signed char* AT8  = (signed char*)(ws + NN);             // 16 MiB
    signed char* Aa8  = (signed char*)(ws + 2 * NN);         // 16 MiB
    signed char* ATa8 = (signed char*)(ws + 3 * NN);         // 16 MiB
    float*       diag = (float*)(ws + 4 * NN);               // 16 KiB
    double*      accs = (double*)(ws + 4 * NN + 4096 * 4);   // 16 B

    diag_kernel<<<dim3(16), 256, 0, stream>>>(ori, clp, u, diag, accs);
    fused_mod_A<<<dim3(N / 32, N / 32), 256, 0, stream>>>(ori, clp, u, diag, out,
                                                          A8, AT8, Aa8, ATa8);
    gemm_trace_i8<<<dim3(N / 128, N / 128, 2), 256, 0, stream>>>(A8, AT8, Aa8, ATa8, accs);
    finalize_kernel<<<1, 1, 0, stream>>>(accs, out);
}